// Round 6
// baseline (234.502 us; speedup 1.0000x reference)
//
#include <hip/hip_runtime.h>
#include <cstdint>
#include <cstddef>

typedef short s16x8 __attribute__((ext_vector_type(8)));
typedef float f32x4 __attribute__((ext_vector_type(4)));

#define MFMA16(a, b, c) __builtin_amdgcn_mfma_f32_16x16x32_bf16((a), (b), (c), 0, 0, 0)

constexpr int LDP = 72;  // padded LDS row stride for attn tiles (2-way bank alias = free)

__device__ __forceinline__ short f2bf(float f) {
    unsigned u = __builtin_bit_cast(unsigned, f);
    u += 0x7FFFu + ((u >> 16) & 1u);   // RNE
    return (short)(u >> 16);
}
__device__ __forceinline__ float bf2f(short s) {
    unsigned u = ((unsigned)(unsigned short)s) << 16;
    return __builtin_bit_cast(float, u);
}
__device__ __forceinline__ unsigned pack2(float a, float b) {
    return (unsigned)(unsigned short)f2bf(a) | ((unsigned)(unsigned short)f2bf(b) << 16);
}
// truncating pack (P in [0,1]: bias <= 1 bf16 ulp) — saves VALU in hot loop
__device__ __forceinline__ unsigned pack2t(float a, float b) {
    unsigned ua = __builtin_bit_cast(unsigned, a);
    unsigned ub = __builtin_bit_cast(unsigned, b);
    return (ua >> 16) | (ub & 0xFFFF0000u);
}

// async 16B/lane global->LDS copy (global_load_lds_dwordx4). LDS dest must be
// wave-uniform base; HW adds lane*16.
__device__ __forceinline__ void async_ld16(const void* g, void* l) {
    __builtin_amdgcn_global_load_lds(
        (const __attribute__((address_space(1))) unsigned int*)g,
        (__attribute__((address_space(3))) unsigned int*)l, 16, 0, 0);
}

// ---------------------------------------------------------------------------
// Kernel 0: fp32 -> bf16 convert of x and all four weights (once per call).
// ---------------------------------------------------------------------------
__global__ __launch_bounds__(256) void convert_kernel(
    const float* __restrict__ x, const float* __restrict__ Wq,
    const float* __restrict__ Wk, const float* __restrict__ Wv,
    const float* __restrict__ Wo, short* __restrict__ xb, short* __restrict__ wb) {
    const size_t f = ((size_t)blockIdx.x * 256 + threadIdx.x) * 8;   // 8 floats/thread
    const float* src;
    short* dst;
    if (f < 4194304) { src = x + f; dst = xb + f; }
    else {
        size_t wo = f - 4194304;
        int seg = (int)(wo >> 20);
        const float* ws4[4] = {Wq, Wk, Wv, Wo};
        src = ws4[seg] + (wo & 1048575u);
        dst = wb + wo;
    }
    float4 a = ((const float4*)src)[0];
    float4 b = ((const float4*)src)[1];
    *(uint4*)dst = make_uint4(pack2(a.x, a.y), pack2(a.z, a.w),
                              pack2(b.x, b.y), pack2(b.z, b.w));
}

// ---------------------------------------------------------------------------
// Kernel 1: QKV projection, m97-structure (128x128 tile, BK=64, async stage).
// Q,K -> [B,H,T,D] bf16; V -> [B,H,D,T] bf16 (pre-transposed).
// ---------------------------------------------------------------------------
__global__ __launch_bounds__(256) void qkv_kernel(
    const short* __restrict__ xb, const short* __restrict__ wb,
    short* __restrict__ Qo, short* __restrict__ Ko, short* __restrict__ VTo) {
    __shared__ __align__(16) short sA[128 * 64];
    __shared__ __align__(16) short sB[128 * 64];
    const int tid = threadIdx.x;
    const int w = tid >> 6, lane = tid & 63, quad = lane >> 4, l15 = lane & 15;
    const int wm = w & 1, wn = w >> 1;
    const int bx = blockIdx.x, by = blockIdx.y;
    const int m0 = by * 128;
    const int nb = bx * 128;

    f32x4 acc[4][4];
#pragma unroll
    for (int i = 0; i < 4; i++)
#pragma unroll
        for (int j = 0; j < 4; j++) acc[i][j] = f32x4{0.f, 0.f, 0.f, 0.f};

    for (int kb = 0; kb < 16; kb++) {
        const int k0 = kb * 64;
        if (kb) __syncthreads();
#pragma unroll
        for (int i = 0; i < 4; i++) {
            int c = i * 256 + tid;             // 16B chunk id
            int row = c >> 3, col8 = (c & 7) * 8;
            async_ld16(xb + (size_t)(m0 + row) * 1024 + k0 + col8,
                       &sA[(i * 256 + w * 64) * 8]);
            async_ld16(wb + (size_t)(nb + row) * 1024 + k0 + col8,
                       &sB[(i * 256 + w * 64) * 8]);
        }
        __syncthreads();
#pragma unroll
        for (int ks = 0; ks < 2; ks++) {
            s16x8 av[4], bv[4];
#pragma unroll
            for (int at = 0; at < 4; at++)
                av[at] = *(const s16x8*)&sA[(wm * 64 + at * 16 + l15) * 64 + ks * 32 + quad * 8];
#pragma unroll
            for (int bt = 0; bt < 4; bt++)
                bv[bt] = *(const s16x8*)&sB[(wn * 64 + bt * 16 + l15) * 64 + ks * 32 + quad * 8];
#pragma unroll
            for (int at = 0; at < 4; at++)
#pragma unroll
                for (int bt = 0; bt < 4; bt++)
                    acc[at][bt] = MFMA16(av[at], bv[bt], acc[at][bt]);
        }
    }

    const int wsel = bx >> 3;                 // 0=q 1=k 2=v
    const int h = (bx & 7) * 2 + wn;          // head (uniform per wave)
    if (wsel == 2) {
#pragma unroll
        for (int at = 0; at < 4; at++) {
            int m = m0 + wm * 64 + at * 16 + quad * 4;
            int b = m >> 11, t0 = m & 2047;
            size_t base = ((size_t)((b * 16 + h) * 64)) * 2048;
#pragma unroll
            for (int bt = 0; bt < 4; bt++) {
                int d = bt * 16 + l15;
                unsigned lo = pack2(acc[at][bt][0], acc[at][bt][1]);
                unsigned hi = pack2(acc[at][bt][2], acc[at][bt][3]);
                *(uint2*)&VTo[base + (size_t)d * 2048 + t0] = make_uint2(lo, hi);
            }
        }
    } else {
        short* Out = (wsel == 0) ? Qo : Ko;
#pragma unroll
        for (int at = 0; at < 4; at++)
#pragma unroll
            for (int r = 0; r < 4; r++) {
                int m = m0 + wm * 64 + at * 16 + quad * 4 + r;
                int b = m >> 11, t = m & 2047;
                size_t base = (((size_t)(b * 16 + h)) * 2048 + t) * 64;
#pragma unroll
                for (int bt = 0; bt < 4; bt++)
                    Out[base + bt * 16 + l15] = f2bf(acc[at][bt][r]);
            }
    }
}

// ---------------------------------------------------------------------------
// Kernel 2: RoPE in-place on Q and K. Q pre-scaled by 0.125*log2(e) (exp2
// domain softmax). Native v_sin/v_cos (revolutions).
// ---------------------------------------------------------------------------
__global__ __launch_bounds__(256) void rope_kernel(short* __restrict__ Q, short* __restrict__ K) {
    const int rid = blockIdx.x * 256 + threadIdx.x;   // 0..131071
    const bool isK = (rid & 65536) != 0;
    short* buf = isK ? K : Q;
    const float sc = isK ? 1.0f : 0.18033688011112042f;   // 1/8 * log2(e)
    const int r2 = rid & 65535;          // bh*2048 + t
    const int t = r2 & 2047;
    short* row = buf + (size_t)r2 * 64;

    unsigned wv[32];
    const uint4* rp = (const uint4*)row;
#pragma unroll
    for (int c = 0; c < 8; c++) {
        uint4 v = rp[c];
        wv[c * 4 + 0] = v.x; wv[c * 4 + 1] = v.y; wv[c * 4 + 2] = v.z; wv[c * 4 + 3] = v.w;
    }
    float y1[32], y2[32];
    const float tf = (float)t;
#pragma unroll
    for (int i = 0; i < 32; i++) {
        float x1 = bf2f((short)(wv[i] & 0xFFFFu));
        float x2 = bf2f((short)(wv[i] >> 16));
        float inv = exp2f((float)i * -0.4152410118609203f);  // 10000^(-i/32), const-folded
        float rev = tf * inv * 0.15915494309189535f;         // fr / 2pi
        rev = rev - floorf(rev);
        float sn = __builtin_amdgcn_sinf(rev);               // sin(rev*2pi) = sin(fr)
        float cs = __builtin_amdgcn_cosf(rev);
        y1[i] = (x1 * cs - x2 * sn) * sc;
        y2[i] = (x1 * sn + x2 * cs) * sc;
    }
    unsigned ow[32];
#pragma unroll
    for (int i = 0; i < 16; i++) ow[i] = pack2(y1[2 * i], y1[2 * i + 1]);
#pragma unroll
    for (int i = 0; i < 16; i++) ow[16 + i] = pack2(y2[2 * i], y2[2 * i + 1]);
    uint4* wp = (uint4*)row;
#pragma unroll
    for (int c = 0; c < 8; c++)
        wp[c] = make_uint4(ow[c * 4 + 0], ow[c * 4 + 1], ow[c * 4 + 2], ow[c * 4 + 3]);
}

// ---------------------------------------------------------------------------
// Kernel 3: causal flash attention, 128-QUERY blocks + key-split partials.
// Block = (qt2, chunk of 8 key-tiles); 40 units/bh, grid 40x32 = 1280 blocks.
// Each wave owns TWO 16-query groups (g=0: rows w*16.., g=1: rows 64+w*16..).
// K/V staged once per key-tile serves both groups (K-frag/V-frag LDS reads
// shared); the two softmax chains are independent straight-line code -> ILP.
// S^T formulation (C-layout col = query). Unnormalized partials + m/l out.
// ---------------------------------------------------------------------------
__global__ __launch_bounds__(256) void attn_kernel(
    const short* __restrict__ Q, const short* __restrict__ K,
    const short* __restrict__ VT, short* __restrict__ paO, float* __restrict__ ml) {
    __shared__ __align__(16) short sQP[128 * LDP];   // Q during prologue, then P
    __shared__ __align__(16) short sK[64 * LDP];
    __shared__ __align__(16) short sVT[64 * LDP];

    const int tid = threadIdx.x;
    const int w = tid >> 6, lane = tid & 63, quad = lane >> 4, l15 = lane & 15;
    const int u = 39 - blockIdx.x;       // largest units first
    const int bh = blockIdx.y;           // 0..31

    int qt2, c;
    if (u < 4)       { qt2 = u; c = 0; }
    else if (u < 12) { int v = u - 4;  qt2 = 4 + (v >> 1); c = v & 1; }
    else if (u < 24) { int v = u - 12; qt2 = 8 + v / 3;    c = v - 3 * (qt2 - 8); }
    else             { int v = u - 24; qt2 = 12 + (v >> 2); c = v & 3; }
    const int ktEnd = 2 * qt2 + 1;
    const int kt0 = c * 8;
    const int kt1 = min(kt0 + 7, ktEnd);

    const short* Qp = Q + (size_t)bh * 2048 * 64;
    const short* Kp = K + (size_t)bh * 2048 * 64;
    const short* Vp = VT + (size_t)bh * 64 * 2048;   // [d][t]

    // stage Q tile (128 rows x 64 dims)
#pragma unroll
    for (int i = 0; i < 4; i++) {
        int p = tid + i * 256;       // 1024 uint4 slots: 128 rows x 8
        int row = p >> 3, c8 = p & 7;
        uint4 v = *(const uint4*)(Qp + (size_t)(qt2 * 128 + row) * 64 + c8 * 8);
        *(uint4*)&sQP[row * LDP + c8 * 8] = v;
    }
    __syncthreads();
    s16x8 aq[2][2];                  // [group][ks] — rows g*64 + w*16 (wave-private)
#pragma unroll
    for (int g = 0; g < 2; g++)
#pragma unroll
        for (int ks = 0; ks < 2; ks++)
            aq[g][ks] = *(const s16x8*)&sQP[(g * 64 + w * 16 + l15) * LDP + ks * 32 + quad * 8];

    f32x4 o[2][4];
#pragma unroll
    for (int g = 0; g < 2; g++)
#pragma unroll
        for (int i = 0; i < 4; i++) o[g][i] = f32x4{0.f, 0.f, 0.f, 0.f};
    float mrun[2] = {-INFINITY, -INFINITY};
    float lrun[2] = {0.f, 0.f};
    const int qidx0 = qt2 * 128 + w * 16 + l15;      // group 0 query (lane l15)
    const int qidx1 = qidx0 + 64;                    // group 1

    for (int kt = kt0; kt <= kt1; kt++) {
        __syncthreads();             // prior iter's sK/sVT readers done
#pragma unroll
        for (int i = 0; i < 2; i++) {
            int p = tid + i * 256;
            int row = p >> 3, c8 = p & 7;
            uint4 kv = *(const uint4*)(Kp + (size_t)(kt * 64 + row) * 64 + c8 * 8);
            *(uint4*)&sK[row * LDP + c8 * 8] = kv;
            uint4 vv = *(const uint4*)(Vp + (size_t)row * 2048 + kt * 64 + c8 * 8);
            *(uint4*)&sVT[row * LDP + c8 * 8] = vv;   // row = d, cols = keys
        }
        __syncthreads();

        // S^T: 64 keys x 16 queries per group; K-fragment shared between groups
        f32x4 sa[2][4];
#pragma unroll
        for (int g = 0; g < 2; g++)
#pragma unroll
            for (int i = 0; i < 4; i++) sa[g][i] = f32x4{0.f, 0.f, 0.f, 0.f};
#pragma unroll
        for (int ks = 0; ks < 2; ks++) {
#pragma unroll
            for (int ct = 0; ct < 4; ct++) {
                s16x8 kf = *(const s16x8*)&sK[(ct * 16 + l15) * LDP + ks * 32 + quad * 8];
                sa[0][ct] = MFMA16(kf, aq[0][ks], sa[0][ct]);
                sa[1][ct] = MFMA16(kf, aq[1][ks], sa[1][ct]);
            }
        }

        float ps[2][4][4];
#pragma unroll
        for (int g = 0; g < 2; g++)
#pragma unroll
            for (int ct = 0; ct < 4; ct++)
#pragma unroll
                for (int r = 0; r < 4; r++) ps[g][ct][r] = sa[g][ct][r];

        if (kt >= 2 * qt2) {         // uniform: only the two diagonal tiles mask
#pragma unroll
            for (int ct = 0; ct < 4; ct++) {
                int kbase = kt * 64 + ct * 16 + quad * 4;
#pragma unroll
                for (int r = 0; r < 4; r++) {
                    if ((kbase + r) > qidx0) ps[0][ct][r] = -INFINITY;
                    if ((kbase + r) > qidx1) ps[1][ct][r] = -INFINITY;
                }
            }
        }

        // online softmax, both groups (independent chains -> ILP)
        float alpha[2];
#pragma unroll
        for (int g = 0; g < 2; g++) {
            float cm[4];
#pragma unroll
            for (int ct = 0; ct < 4; ct++)
                cm[ct] = fmaxf(fmaxf(ps[g][ct][0], ps[g][ct][1]), fmaxf(ps[g][ct][2], ps[g][ct][3]));
            float mx = fmaxf(fmaxf(cm[0], cm[1]), fmaxf(cm[2], cm[3]));
            mx = fmaxf(mx, __shfl_xor(mx, 16));
            mx = fmaxf(mx, __shfl_xor(mx, 32));
            float mnew = fmaxf(mrun[g], mx);
            alpha[g] = exp2f(mrun[g] - mnew);
            mrun[g] = mnew;
            float cs[4];
#pragma unroll
            for (int ct = 0; ct < 4; ct++) {
#pragma unroll
                for (int r = 0; r < 4; r++) ps[g][ct][r] = exp2f(ps[g][ct][r] - mnew);
                cs[ct] = (ps[g][ct][0] + ps[g][ct][1]) + (ps[g][ct][2] + ps[g][ct][3]);
            }
            float psum = (cs[0] + cs[1]) + (cs[2] + cs[3]);
            psum += __shfl_xor(psum, 16);
            psum += __shfl_xor(psum, 32);
            lrun[g] = lrun[g] * alpha[g] + psum;
        }

        // rescale O (alpha per query l15 -> broadcast to query rows quad*4+r)
#pragma unroll
        for (int g = 0; g < 2; g++) {
            float arow[4];
#pragma unroll
            for (int r = 0; r < 4; r++) arow[r] = __shfl(alpha[g], quad * 4 + r);
#pragma unroll
            for (int ct = 0; ct < 4; ct++)
#pragma unroll
                for (int r = 0; r < 4; r++) o[g][ct][r] *= arow[r];
        }

        // P^T -> sQP rows (wave-private: row g*64 + w*16 + l15)
#pragma unroll
        for (int g = 0; g < 2; g++)
#pragma unroll
            for (int ct = 0; ct < 4; ct++) {
                unsigned lo = pack2t(ps[g][ct][0], ps[g][ct][1]);
                unsigned hi = pack2t(ps[g][ct][2], ps[g][ct][3]);
                *(uint2*)&sQP[(g * 64 + w * 16 + l15) * LDP + ct * 16 + quad * 4] = make_uint2(lo, hi);
            }
        // no barrier: rows are wave-private, same-wave DS ops in-order

        // O += P V  (V-fragment shared between groups)
#pragma unroll
        for (int ks2 = 0; ks2 < 2; ks2++) {
            s16x8 pa0 = *(const s16x8*)&sQP[(w * 16 + l15) * LDP + ks2 * 32 + quad * 8];
            s16x8 pa1 = *(const s16x8*)&sQP[(64 + w * 16 + l15) * LDP + ks2 * 32 + quad * 8];
#pragma unroll
            for (int ct = 0; ct < 4; ct++) {
                s16x8 vb = *(const s16x8*)&sVT[(ct * 16 + l15) * LDP + ks2 * 32 + quad * 8];
                o[0][ct] = MFMA16(pa0, vb, o[0][ct]);
                o[1][ct] = MFMA16(pa1, vb, o[1][ct]);
            }
        }
    }

    // epilogue: UNNORMALIZED partial O (bf16, 128x64), m/l (fp32, 128+128)
    const size_t pbase = ((size_t)(bh * 40 + u)) * 8192;
#pragma unroll
    for (int g = 0; g < 2; g++)
#pragma unroll
        for (int r = 0; r < 4; r++) {
            int row = g * 64 + w * 16 + quad * 4 + r;
#pragma unroll
            for (int ct = 0; ct < 4; ct++)
                paO[pbase + row * 64 + ct * 16 + l15] = f2bf(o[g][ct][r]);
        }
    if (quad == 0) {
        int mlbase = (bh * 40 + u) * 256;
#pragma unroll
        for (int g = 0; g < 2; g++) {
            ml[mlbase + g * 64 + w * 16 + l15] = mrun[g];
            ml[mlbase + 128 + g * 64 + w * 16 + l15] = lrun[g];
        }
    }
}

// ---------------------------------------------------------------------------
// Kernel 3b: combine partials. Block = (qt2, bh); merges nch = qt2/4+1
// 128-row partials: M = max m_i; L = sum l_i*2^(m_i-M); Y = sum O_i*2^(m_i-M)/L.
// ---------------------------------------------------------------------------
__global__ __launch_bounds__(256) void combine_kernel(
    const short* __restrict__ paO, const float* __restrict__ ml, short* __restrict__ Y) {
    const int qt2 = blockIdx.x, bh = blockIdx.y;
    const int b = bh >> 4, h = bh & 15;
    const int nch = (qt2 >> 2) + 1;
    int base;
    if (qt2 < 4) base = qt2;
    else if (qt2 < 8) base = 4 + 2 * (qt2 - 4);
    else if (qt2 < 12) base = 12 + 3 * (qt2 - 8);
    else base = 24 + 4 * (qt2 - 12);

    const int row = threadIdx.x >> 1;          // 0..127
    const int cq = (threadIdx.x & 1) * 32;     // 32 cols per thread

    float mi[4], li[4];
    float M = -INFINITY;
    for (int i = 0; i < nch; i++) {
        int mlbase = (bh * 40 + base + i) * 256;
        mi[i] = ml[mlbase + row];
        li[i] = ml[mlbase + 128 + row];
        M = fmaxf(M, mi[i]);
    }
    float L = 0.f, ai[4];
    for (int i = 0; i < nch; i++) {
        ai[i] = exp2f(mi[i] - M);
        L += li[i] * ai[i];
    }
    const float inv = 1.0f / L;

    float acc[32];
#pragma unroll
    for (int j = 0; j < 32; j++) acc[j] = 0.f;
    for (int i = 0; i < nch; i++) {
        const short* p = paO + ((size_t)(bh * 40 + base + i)) * 8192 + row * 64 + cq;
#pragma unroll
        for (int q = 0; q < 4; q++) {
            uint4 v = ((const uint4*)p)[q];
            unsigned vs[4] = {v.x, v.y, v.z, v.w};
#pragma unroll
            for (int j = 0; j < 4; j++) {
                acc[q * 8 + 2 * j + 0] += bf2f((short)(vs[j] & 0xFFFFu)) * ai[i];
                acc[q * 8 + 2 * j + 1] += bf2f((short)(vs[j] >> 16)) * ai[i];
            }
        }
    }
    const int t = qt2 * 128 + row;
    short* yp = Y + ((size_t)(b * 2048 + t)) * 1024 + h * 64 + cq;
#pragma unroll
    for (int q = 0; q < 4; q++) {
        unsigned ow[4];
#pragma unroll
        for (int j = 0; j < 4; j++)
            ow[j] = pack2(acc[q * 8 + 2 * j] * inv, acc[q * 8 + 2 * j + 1] * inv);
        ((uint4*)yp)[q] = make_uint4(ow[0], ow[1], ow[2], ow[3]);
    }
}

// ---------------------------------------------------------------------------
// Kernel 4: output projection, 64x128 tiles -> grid (8,64)=512 blocks (2/CU).
// Wave w owns a 64x32 output slab. fp32 out.
// ---------------------------------------------------------------------------
__global__ __launch_bounds__(256) void oproj_kernel(
    const short* __restrict__ Yb, const short* __restrict__ Wob, float* __restrict__ out) {
    __shared__ __align__(16) short sA[64 * 64];
    __shared__ __align__(16) short sB[128 * 64];
    const int tid = threadIdx.x;
    const int w = tid >> 6, lane = tid & 63, quad = lane >> 4, l15 = lane & 15;
    const int m0 = blockIdx.y * 64;
    const int nb = blockIdx.x * 128;

    f32x4 acc[4][2];
#pragma unroll
    for (int i = 0; i < 4; i++)
#pragma unroll
        for (int j = 0; j < 2; j++) acc[i][j] = f32x4{0.f, 0.f, 0.f, 0.f};

    for (int kb = 0; kb < 16; kb++) {
        const int k0 = kb * 64;
        if (kb) __syncthreads();
#pragma unroll
        for (int i = 0; i < 2; i++) {      // A: 64x64 shorts = 512 chunks
            int c = i * 256 + tid;
            int row = c >> 3, col8 = (c & 7) * 8;
            async_ld16(Yb + (size_t)(m0 + row) * 1024 + k0 + col8,
                       &sA[(i * 256 + w * 64) * 8]);
        }
#pragma unroll
        for (int i = 0; i < 4; i++) {      // B: 128x64 shorts = 1024 chunks
            int c = i * 256 + tid;
            int row = c >> 3, col8 = (c & 7) * 8;
            async_ld16(Wob + (size_t)(nb + row) * 1024 + k0 + col8,
                       &sB[(i * 256 + w * 64) * 8]);
        }
        __syncthreads();
#pragma unroll
        for (int ks = 0; ks < 2; ks++) {
            s16x8 av[4], bv[2];
#pragma unroll
            for (int at = 0; at < 4; at++)
                av[at] = *(const s16x8*)&sA[(at * 16 + l15) * 64 + ks * 32 + quad * 8];
#pragma unroll
            for (int bt = 0; bt < 2; bt++)
                bv[bt] = *(const s16x8*)&sB[(w * 32 + bt * 16 + l15) * 64 + ks * 32 + quad * 8];
#pragma unroll
            for (int at = 0; at < 4; at++)
#pragma unroll
                for (int bt = 0; bt < 2; bt++)
                    acc[at][bt] = MFMA16(av[at], bv[bt], acc[at][bt]);
        }
    }
#pragma unroll
    for (int at = 0; at < 4; at++)
#pragma unroll
        for (int r = 0; r < 4; r++) {
            int m = m0 + at * 16 + quad * 4 + r;
#pragma unroll
            for (int bt = 0; bt < 2; bt++) {
                int n = nb + w * 32 + bt * 16 + l15;
                out[(size_t)m * 1024 + n] = acc[at][bt][r];
            }
        }
}

extern "C" void kernel_launch(void* const* d_in, const int* in_sizes, int n_in,
                              void* d_out, int out_size, void* d_ws, size_t ws_size,
                              hipStream_t stream) {
    (void)in_sizes; (void)n_in; (void)out_size; (void)ws_size;
    const float* x  = (const float*)d_in[0];
    const float* Wq = (const float*)d_in[1];
    const float* Wk = (const float*)d_in[2];
    const float* Wv = (const float*)d_in[3];
    const float* Wo = (const float*)d_in[4];
    float* out = (float*)d_out;

    const size_t NE = (size_t)2 * 16 * 2048 * 64;   // 4M elems per tensor
    short* Q   = (short*)d_ws;
    short* K   = Q + NE;
    short* VT  = K + NE;          // [B,H,D,T]
    short* Y   = VT + NE;         // attn output [B,T,C] bf16
    short* xb  = Y;               // x bf16 ALIASES Y: consumed by qkv before combine writes Y
    short* wb  = Y + NE;          // [Wq|Wk|Wv|Wo] bf16, 4M elems
    short* paO = wb + NE;         // partial O: 32 bh x 40 units x 128x64 bf16 = 21 MB
    float* ml  = (float*)(paO + (size_t)32 * 40 * 8192);   // m,l: 32x40x256 fp32

    convert_kernel<<<4096, 256, 0, stream>>>(x, Wq, Wk, Wv, Wo, xb, wb);
    qkv_kernel<<<dim3(24, 32), 256, 0, stream>>>(xb, wb, Q, K, VT);
    rope_kernel<<<512, 256, 0, stream>>>(Q, K);
    attn_kernel<<<dim3(40, 32), 256, 0, stream>>>(Q, K, VT, paO, ml);
    combine_kernel<<<dim3(16, 32), 256, 0, stream>>>(paO, ml, Y);
    oproj_kernel<<<dim3(8, 64), 256, 0, stream>>>(Y, wb + 3 * 1048576, out);
}

// Round 7
// 212.359 us; speedup vs baseline: 1.1043x; 1.1043x over previous
//
#include <hip/hip_runtime.h>
#include <cstdint>
#include <cstddef>

typedef short s16x8 __attribute__((ext_vector_type(8)));
typedef float f32x4 __attribute__((ext_vector_type(4)));

#define MFMA16(a, b, c) __builtin_amdgcn_mfma_f32_16x16x32_bf16((a), (b), (c), 0, 0, 0)

constexpr int LDP = 72;   // stride for 64-col tiles (bf16): staging conflict-free, frag reads 2-way
constexpr int LDW = 136;  // stride for 128-col tiles (bf16): same properties

__device__ __forceinline__ short f2bf(float f) {
    unsigned u = __builtin_bit_cast(unsigned, f);
    u += 0x7FFFu + ((u >> 16) & 1u);   // RNE
    return (short)(u >> 16);
}
__device__ __forceinline__ float bf2f(short s) {
    unsigned u = ((unsigned)(unsigned short)s) << 16;
    return __builtin_bit_cast(float, u);
}
__device__ __forceinline__ unsigned pack2(float a, float b) {
    return (unsigned)(unsigned short)f2bf(a) | ((unsigned)(unsigned short)f2bf(b) << 16);
}
// truncating pack (P in [0,1]: bias <= 1 bf16 ulp) — saves VALU in hot loop
__device__ __forceinline__ unsigned pack2t(float a, float b) {
    unsigned ua = __builtin_bit_cast(unsigned, a);
    unsigned ub = __builtin_bit_cast(unsigned, b);
    return (ua >> 16) | (ub & 0xFFFF0000u);
}

// async 16B/lane global->LDS copy (global_load_lds_dwordx4). LDS dest must be
// wave-uniform base; HW adds lane*16.
__device__ __forceinline__ void async_ld16(const void* g, void* l) {
    __builtin_amdgcn_global_load_lds(
        (const __attribute__((address_space(1))) unsigned int*)g,
        (__attribute__((address_space(3))) unsigned int*)l, 16, 0, 0);
}

// ---------------------------------------------------------------------------
// Kernel 0: fp32 -> bf16 convert of x and all four weights (once per call).
// ---------------------------------------------------------------------------
__global__ __launch_bounds__(256) void convert_kernel(
    const float* __restrict__ x, const float* __restrict__ Wq,
    const float* __restrict__ Wk, const float* __restrict__ Wv,
    const float* __restrict__ Wo, short* __restrict__ xb, short* __restrict__ wb) {
    const size_t f = ((size_t)blockIdx.x * 256 + threadIdx.x) * 8;   // 8 floats/thread
    const float* src;
    short* dst;
    if (f < 4194304) { src = x + f; dst = xb + f; }
    else {
        size_t wo = f - 4194304;
        int seg = (int)(wo >> 20);
        const float* ws4[4] = {Wq, Wk, Wv, Wo};
        src = ws4[seg] + (wo & 1048575u);
        dst = wb + wo;
    }
    float4 a = ((const float4*)src)[0];
    float4 b = ((const float4*)src)[1];
    *(uint4*)dst = make_uint4(pack2(a.x, a.y), pack2(a.z, a.w),
                              pack2(b.x, b.y), pack2(b.z, b.w));
}

// ---------------------------------------------------------------------------
// Kernel 1: QKV projection, m97-structure (128x128 tile, BK=64, async stage).
// Q,K -> [B,H,T,D] bf16; V -> [B,H,D,T] bf16 (pre-transposed).
// ---------------------------------------------------------------------------
__global__ __launch_bounds__(256) void qkv_kernel(
    const short* __restrict__ xb, const short* __restrict__ wb,
    short* __restrict__ Qo, short* __restrict__ Ko, short* __restrict__ VTo) {
    __shared__ __align__(16) short sA[128 * 64];
    __shared__ __align__(16) short sB[128 * 64];
    const int tid = threadIdx.x;
    const int w = tid >> 6, lane = tid & 63, quad = lane >> 4, l15 = lane & 15;
    const int wm = w & 1, wn = w >> 1;
    const int bx = blockIdx.x, by = blockIdx.y;
    const int m0 = by * 128;
    const int nb = bx * 128;

    f32x4 acc[4][4];
#pragma unroll
    for (int i = 0; i < 4; i++)
#pragma unroll
        for (int j = 0; j < 4; j++) acc[i][j] = f32x4{0.f, 0.f, 0.f, 0.f};

    for (int kb = 0; kb < 16; kb++) {
        const int k0 = kb * 64;
        if (kb) __syncthreads();
#pragma unroll
        for (int i = 0; i < 4; i++) {
            int c = i * 256 + tid;             // 16B chunk id
            int row = c >> 3, col8 = (c & 7) * 8;
            async_ld16(xb + (size_t)(m0 + row) * 1024 + k0 + col8,
                       &sA[(i * 256 + w * 64) * 8]);
            async_ld16(wb + (size_t)(nb + row) * 1024 + k0 + col8,
                       &sB[(i * 256 + w * 64) * 8]);
        }
        __syncthreads();
#pragma unroll
        for (int ks = 0; ks < 2; ks++) {
            s16x8 av[4], bv[4];
#pragma unroll
            for (int at = 0; at < 4; at++)
                av[at] = *(const s16x8*)&sA[(wm * 64 + at * 16 + l15) * 64 + ks * 32 + quad * 8];
#pragma unroll
            for (int bt = 0; bt < 4; bt++)
                bv[bt] = *(const s16x8*)&sB[(wn * 64 + bt * 16 + l15) * 64 + ks * 32 + quad * 8];
#pragma unroll
            for (int at = 0; at < 4; at++)
#pragma unroll
                for (int bt = 0; bt < 4; bt++)
                    acc[at][bt] = MFMA16(av[at], bv[bt], acc[at][bt]);
        }
    }

    const int wsel = bx >> 3;                 // 0=q 1=k 2=v
    const int h = (bx & 7) * 2 + wn;          // head (uniform per wave)
    if (wsel == 2) {
#pragma unroll
        for (int at = 0; at < 4; at++) {
            int m = m0 + wm * 64 + at * 16 + quad * 4;
            int b = m >> 11, t0 = m & 2047;
            size_t base = ((size_t)((b * 16 + h) * 64)) * 2048;
#pragma unroll
            for (int bt = 0; bt < 4; bt++) {
                int d = bt * 16 + l15;
                unsigned lo = pack2(acc[at][bt][0], acc[at][bt][1]);
                unsigned hi = pack2(acc[at][bt][2], acc[at][bt][3]);
                *(uint2*)&VTo[base + (size_t)d * 2048 + t0] = make_uint2(lo, hi);
            }
        }
    } else {
        short* Out = (wsel == 0) ? Qo : Ko;
#pragma unroll
        for (int at = 0; at < 4; at++)
#pragma unroll
            for (int r = 0; r < 4; r++) {
                int m = m0 + wm * 64 + at * 16 + quad * 4 + r;
                int b = m >> 11, t = m & 2047;
                size_t base = (((size_t)(b * 16 + h)) * 2048 + t) * 64;
#pragma unroll
                for (int bt = 0; bt < 4; bt++)
                    Out[base + bt * 16 + l15] = f2bf(acc[at][bt][r]);
            }
    }
}

// ---------------------------------------------------------------------------
// Kernel 2: RoPE in-place on Q and K. Q pre-scaled by 0.125*log2(e) (exp2
// domain softmax). Native v_sin/v_cos (revolutions).
// ---------------------------------------------------------------------------
__global__ __launch_bounds__(256) void rope_kernel(short* __restrict__ Q, short* __restrict__ K) {
    const int rid = blockIdx.x * 256 + threadIdx.x;   // 0..131071
    const bool isK = (rid & 65536) != 0;
    short* buf = isK ? K : Q;
    const float sc = isK ? 1.0f : 0.18033688011112042f;   // 1/8 * log2(e)
    const int r2 = rid & 65535;          // bh*2048 + t
    const int t = r2 & 2047;
    short* row = buf + (size_t)r2 * 64;

    unsigned wv[32];
    const uint4* rp = (const uint4*)row;
#pragma unroll
    for (int c = 0; c < 8; c++) {
        uint4 v = rp[c];
        wv[c * 4 + 0] = v.x; wv[c * 4 + 1] = v.y; wv[c * 4 + 2] = v.z; wv[c * 4 + 3] = v.w;
    }
    float y1[32], y2[32];
    const float tf = (float)t;
#pragma unroll
    for (int i = 0; i < 32; i++) {
        float x1 = bf2f((short)(wv[i] & 0xFFFFu));
        float x2 = bf2f((short)(wv[i] >> 16));
        float inv = exp2f((float)i * -0.4152410118609203f);  // 10000^(-i/32), const-folded
        float rev = tf * inv * 0.15915494309189535f;         // fr / 2pi
        rev = rev - floorf(rev);
        float sn = __builtin_amdgcn_sinf(rev);               // sin(rev*2pi) = sin(fr)
        float cs = __builtin_amdgcn_cosf(rev);
        y1[i] = (x1 * cs - x2 * sn) * sc;
        y2[i] = (x1 * sn + x2 * cs) * sc;
    }
    unsigned ow[32];
#pragma unroll
    for (int i = 0; i < 16; i++) ow[i] = pack2(y1[2 * i], y1[2 * i + 1]);
#pragma unroll
    for (int i = 0; i < 16; i++) ow[16 + i] = pack2(y2[2 * i], y2[2 * i + 1]);
    uint4* wp = (uint4*)row;
#pragma unroll
    for (int c = 0; c < 8; c++)
        wp[c] = make_uint4(ow[c * 4 + 0], ow[c * 4 + 1], ow[c * 4 + 2], ow[c * 4 + 3]);
}

// ---------------------------------------------------------------------------
// Kernel 3: causal flash attention — round-4 structure (64 queries, 80 units,
// inline staging) with 128-KEY blocks: one softmax chain per 128 keys instead
// of two, half the barriers/staging loops per key, 32 MFMA per chain.
// Unit = (qt, chunk of 4 key-blocks = 512 keys); same 80-unit map as round 4.
// S^T formulation (C col = query). Unnormalized partials + m/l out.
// ---------------------------------------------------------------------------
__global__ __launch_bounds__(256) void attn_kernel(
    const short* __restrict__ Q, const short* __restrict__ K,
    const short* __restrict__ VT, short* __restrict__ paO, float* __restrict__ ml) {
    __shared__ __align__(16) short sQP[64 * LDW];   // Q (64x64) then P (64q x 128k)
    __shared__ __align__(16) short sK[128 * LDP];   // 128 keys x 64 d
    __shared__ __align__(16) short sVT[64 * LDW];   // 64 d x 128 keys

    const int tid = threadIdx.x;
    const int w = tid >> 6, lane = tid & 63, quad = lane >> 4, l15 = lane & 15;
    const int u = 79 - blockIdx.x;       // largest-qt units first
    const int bh = blockIdx.y;           // 0..31

    int qt, c;
    if (u < 8)       { qt = u; c = 0; }
    else if (u < 24) { int v = u - 8;  qt = 8 + (v >> 1); c = v & 1; }
    else if (u < 48) { int v = u - 24; qt = 16 + v / 3;   c = v - 3 * (qt - 16); }
    else             { int v = u - 48; qt = 24 + (v >> 2); c = v & 3; }
    const int kbDiag = qt >> 1;              // 128-key block containing the diagonal
    const int kb0 = c * 4;
    const int kb1 = min(kb0 + 3, kbDiag);

    const short* Qp = Q + (size_t)bh * 2048 * 64;
    const short* Kp = K + (size_t)bh * 2048 * 64;
    const short* Vp = VT + (size_t)bh * 64 * 2048;   // [d][t]

    // stage Q tile (64 rows x 64 dims) into sQP (stride LDW)
#pragma unroll
    for (int i = 0; i < 2; i++) {
        int p = tid + i * 256;       // 512 uint4 slots: 64 rows x 8
        int row = p >> 3, c8 = p & 7;
        uint4 v = *(const uint4*)(Qp + (size_t)(qt * 64 + row) * 64 + c8 * 8);
        *(uint4*)&sQP[row * LDW + c8 * 8] = v;
    }
    __syncthreads();
    s16x8 aq[2];
#pragma unroll
    for (int ks = 0; ks < 2; ks++)
        aq[ks] = *(const s16x8*)&sQP[(w * 16 + l15) * LDW + ks * 32 + quad * 8];

    f32x4 o[4];
#pragma unroll
    for (int i = 0; i < 4; i++) o[i] = f32x4{0.f, 0.f, 0.f, 0.f};
    float mrun = -INFINITY;          // per query (this lane's l15 column)
    float lrun = 0.f;
    const int q_idx = qt * 64 + w * 16 + l15;

    for (int kb = kb0; kb <= kb1; kb++) {
        __syncthreads();             // prior iter's readers done (covers aq reads iter 0)
        // stage K (128 keys x 64 d) and V^T (64 d x 128 keys): 4+4 uint4/thread
#pragma unroll
        for (int i = 0; i < 4; i++) {
            int p = tid + i * 256;
            {   // sK
                int row = p >> 3, c8 = p & 7;
                uint4 kv = *(const uint4*)(Kp + (size_t)(kb * 128 + row) * 64 + c8 * 8);
                *(uint4*)&sK[row * LDP + c8 * 8] = kv;
            }
            {   // sVT
                int row = p >> 4, c16 = p & 15;
                uint4 vv = *(const uint4*)(Vp + (size_t)row * 2048 + kb * 128 + c16 * 8);
                *(uint4*)&sVT[row * LDW + c16 * 8] = vv;
            }
        }
        __syncthreads();

        // S^T: 128 keys x 16 queries per wave. A = K rows (keys), B = Q^T.
        f32x4 sa[8];
#pragma unroll
        for (int i = 0; i < 8; i++) sa[i] = f32x4{0.f, 0.f, 0.f, 0.f};
#pragma unroll
        for (int ks = 0; ks < 2; ks++) {
#pragma unroll
            for (int ct = 0; ct < 8; ct++) {
                s16x8 kf = *(const s16x8*)&sK[(ct * 16 + l15) * LDP + ks * 32 + quad * 8];
                sa[ct] = MFMA16(kf, aq[ks], sa[ct]);
            }
        }

        float ps[8][4];
#pragma unroll
        for (int ct = 0; ct < 8; ct++)
#pragma unroll
            for (int r = 0; r < 4; r++) ps[ct][r] = sa[ct][r];

        if (kb == kbDiag) {          // uniform branch: only the diagonal block masks
#pragma unroll
            for (int ct = 0; ct < 8; ct++) {
                int kbase = kb * 128 + ct * 16 + quad * 4;
#pragma unroll
                for (int r = 0; r < 4; r++)
                    if ((kbase + r) > q_idx) ps[ct][r] = -INFINITY;
            }
        }

        // max over this query's 128 keys: in-lane tree (32 vals) + xor16/32
        float cm[8];
#pragma unroll
        for (int ct = 0; ct < 8; ct++)
            cm[ct] = fmaxf(fmaxf(ps[ct][0], ps[ct][1]), fmaxf(ps[ct][2], ps[ct][3]));
        float mx = fmaxf(fmaxf(fmaxf(cm[0], cm[1]), fmaxf(cm[2], cm[3])),
                         fmaxf(fmaxf(cm[4], cm[5]), fmaxf(cm[6], cm[7])));
        mx = fmaxf(mx, __shfl_xor(mx, 16));
        mx = fmaxf(mx, __shfl_xor(mx, 32));
        float mnew = fmaxf(mrun, mx);
        float alpha = exp2f(mrun - mnew);
        mrun = mnew;
#pragma unroll
        for (int ct = 0; ct < 8; ct++) {
#pragma unroll
            for (int r = 0; r < 4; r++) ps[ct][r] = exp2f(ps[ct][r] - mnew);
            cm[ct] = (ps[ct][0] + ps[ct][1]) + (ps[ct][2] + ps[ct][3]);
        }
        float psum = ((cm[0] + cm[1]) + (cm[2] + cm[3])) + ((cm[4] + cm[5]) + (cm[6] + cm[7]));
        psum += __shfl_xor(psum, 16);
        psum += __shfl_xor(psum, 32);
        lrun = lrun * alpha + psum;

        // broadcast alpha (per query l15) to O rows (query quad*4+r)
        float arow[4];
#pragma unroll
        for (int r = 0; r < 4; r++) arow[r] = __shfl(alpha, quad * 4 + r);
#pragma unroll
        for (int ct = 0; ct < 4; ct++)
#pragma unroll
            for (int r = 0; r < 4; r++) o[ct][r] *= arow[r];

        // P^T (C-layout) -> sQP rows = query (wave-private), 8x ds_write_b64
#pragma unroll
        for (int ct = 0; ct < 8; ct++) {
            unsigned lo = pack2t(ps[ct][0], ps[ct][1]);
            unsigned hi = pack2t(ps[ct][2], ps[ct][3]);
            *(uint2*)&sQP[(w * 16 + l15) * LDW + ct * 16 + quad * 4] = make_uint2(lo, hi);
        }
        // no barrier: rows are wave-private, same-wave DS ops in-order

        // O += P V  (A = P rows=query, k = 128 keys; B = V^T rows = d)
#pragma unroll
        for (int ks2 = 0; ks2 < 4; ks2++) {
            s16x8 pa = *(const s16x8*)&sQP[(w * 16 + l15) * LDW + ks2 * 32 + quad * 8];
#pragma unroll
            for (int ct = 0; ct < 4; ct++) {
                s16x8 vb = *(const s16x8*)&sVT[(ct * 16 + l15) * LDW + ks2 * 32 + quad * 8];
                o[ct] = MFMA16(pa, vb, o[ct]);
            }
        }
    }

    // epilogue: UNNORMALIZED partial O (bf16), m/l (fp32, per query row)
    const size_t pbase = ((size_t)(bh * 80 + u)) * 4096;
#pragma unroll
    for (int r = 0; r < 4; r++) {
        int row = w * 16 + quad * 4 + r;
#pragma unroll
        for (int ct = 0; ct < 4; ct++)
            paO[pbase + row * 64 + ct * 16 + l15] = f2bf(o[ct][r]);
    }
    if (quad == 0) {
        int mlbase = (bh * 80 + u) * 128;
        ml[mlbase + w * 16 + l15] = mrun;
        ml[mlbase + 64 + w * 16 + l15] = lrun;
    }
}

// ---------------------------------------------------------------------------
// Kernel 3b: combine partials. Block = (qt, bh); merges nch = qt/8+1 partials.
// ---------------------------------------------------------------------------
__global__ __launch_bounds__(256) void combine_kernel(
    const short* __restrict__ paO, const float* __restrict__ ml, short* __restrict__ Y) {
    const int qt = blockIdx.x, bh = blockIdx.y;
    const int b = bh >> 4, h = bh & 15;
    const int nch = (qt >> 3) + 1;
    int base;
    if (qt < 8) base = qt;
    else if (qt < 16) base = 8 + 2 * (qt - 8);
    else if (qt < 24) base = 24 + 3 * (qt - 16);
    else base = 48 + 4 * (qt - 24);

    const int row = threadIdx.x >> 2;
    const int cq = (threadIdx.x & 3) * 16;

    float mi[4], li[4];
    float M = -INFINITY;
    for (int i = 0; i < nch; i++) {
        int mlbase = (bh * 80 + base + i) * 128;
        mi[i] = ml[mlbase + row];
        li[i] = ml[mlbase + 64 + row];
        M = fmaxf(M, mi[i]);
    }
    float L = 0.f, ai[4];
    for (int i = 0; i < nch; i++) {
        ai[i] = exp2f(mi[i] - M);
        L += li[i] * ai[i];
    }
    const float inv = 1.0f / L;

    float acc[16];
#pragma unroll
    for (int j = 0; j < 16; j++) acc[j] = 0.f;
    for (int i = 0; i < nch; i++) {
        const short* p = paO + ((size_t)(bh * 80 + base + i)) * 4096 + row * 64 + cq;
        uint4 v0 = ((const uint4*)p)[0];
        uint4 v1 = ((const uint4*)p)[1];
        unsigned vs[8] = {v0.x, v0.y, v0.z, v0.w, v1.x, v1.y, v1.z, v1.w};
#pragma unroll
        for (int j = 0; j < 8; j++) {
            acc[2 * j + 0] += bf2f((short)(vs[j] & 0xFFFFu)) * ai[i];
            acc[2 * j + 1] += bf2f((short)(vs[j] >> 16)) * ai[i];
        }
    }
    const int t = qt * 64 + row;
    short* yp = Y + ((size_t)(b * 2048 + t)) * 1024 + h * 64 + cq;
    unsigned ow[8];
#pragma unroll
    for (int j = 0; j < 8; j++) ow[j] = pack2(acc[2 * j] * inv, acc[2 * j + 1] * inv);
    ((uint4*)yp)[0] = make_uint4(ow[0], ow[1], ow[2], ow[3]);
    ((uint4*)yp)[1] = make_uint4(ow[4], ow[5], ow[6], ow[7]);
}

// ---------------------------------------------------------------------------
// Kernel 4: output projection, 64x128 tiles -> grid (8,64)=512 blocks (2/CU).
// Wave w owns a 64x32 output slab. fp32 out.
// ---------------------------------------------------------------------------
__global__ __launch_bounds__(256) void oproj_kernel(
    const short* __restrict__ Yb, const short* __restrict__ Wob, float* __restrict__ out) {
    __shared__ __align__(16) short sA[64 * 64];
    __shared__ __align__(16) short sB[128 * 64];
    const int tid = threadIdx.x;
    const int w = tid >> 6, lane = tid & 63, quad = lane >> 4, l15 = lane & 15;
    const int m0 = blockIdx.y * 64;
    const int nb = blockIdx.x * 128;

    f32x4 acc[4][2];
#pragma unroll
    for (int i = 0; i < 4; i++)
#pragma unroll
        for (int j = 0; j < 2; j++) acc[i][j] = f32x4{0.f, 0.f, 0.f, 0.f};

    for (int kb = 0; kb < 16; kb++) {
        const int k0 = kb * 64;
        if (kb) __syncthreads();
#pragma unroll
        for (int i = 0; i < 2; i++) {      // A: 64x64 shorts = 512 chunks
            int c = i * 256 + tid;
            int row = c >> 3, col8 = (c & 7) * 8;
            async_ld16(Yb + (size_t)(m0 + row) * 1024 + k0 + col8,
                       &sA[(i * 256 + w * 64) * 8]);
        }
#pragma unroll
        for (int i = 0; i < 4; i++) {      // B: 128x64 shorts = 1024 chunks
            int c = i * 256 + tid;
            int row = c >> 3, col8 = (c & 7) * 8;
            async_ld16(Wob + (size_t)(nb + row) * 1024 + k0 + col8,
                       &sB[(i * 256 + w * 64) * 8]);
        }
        __syncthreads();
#pragma unroll
        for (int ks = 0; ks < 2; ks++) {
            s16x8 av[4], bv[2];
#pragma unroll
            for (int at = 0; at < 4; at++)
                av[at] = *(const s16x8*)&sA[(at * 16 + l15) * 64 + ks * 32 + quad * 8];
#pragma unroll
            for (int bt = 0; bt < 2; bt++)
                bv[bt] = *(const s16x8*)&sB[(w * 32 + bt * 16 + l15) * 64 + ks * 32 + quad * 8];
#pragma unroll
            for (int at = 0; at < 4; at++)
#pragma unroll
                for (int bt = 0; bt < 2; bt++)
                    acc[at][bt] = MFMA16(av[at], bv[bt], acc[at][bt]);
        }
    }
#pragma unroll
    for (int at = 0; at < 4; at++)
#pragma unroll
        for (int r = 0; r < 4; r++) {
            int m = m0 + at * 16 + quad * 4 + r;
#pragma unroll
            for (int bt = 0; bt < 2; bt++) {
                int n = nb + w * 32 + bt * 16 + l15;
                out[(size_t)m * 1024 + n] = acc[at][bt][r];
            }
        }
}

extern "C" void kernel_launch(void* const* d_in, const int* in_sizes, int n_in,
                              void* d_out, int out_size, void* d_ws, size_t ws_size,
                              hipStream_t stream) {
    (void)in_sizes; (void)n_in; (void)out_size; (void)ws_size;
    const float* x  = (const float*)d_in[0];
    const float* Wq = (const float*)d_in[1];
    const float* Wk = (const float*)d_in[2];
    const float* Wv = (const float*)d_in[3];
    const float* Wo = (const float*)d_in[4];
    float* out = (float*)d_out;

    const size_t NE = (size_t)2 * 16 * 2048 * 64;   // 4M elems per tensor
    short* Q   = (short*)d_ws;
    short* K   = Q + NE;
    short* VT  = K + NE;          // [B,H,D,T]
    short* Y   = VT + NE;         // attn output [B,T,C] bf16
    short* xb  = Y;               // x bf16 ALIASES Y: consumed by qkv before combine writes Y
    short* wb  = Y + NE;          // [Wq|Wk|Wv|Wo] bf16, 4M elems
    short* paO = wb + NE;         // partial O: 32 bh x 80 units x 64x64 bf16 = 21 MB
    float* ml  = (float*)(paO + (size_t)32 * 80 * 4096);   // m,l: 32x80x128 fp32

    convert_kernel<<<4096, 256, 0, stream>>>(x, Wq, Wk, Wv, Wo, xb, wb);
    qkv_kernel<<<dim3(24, 32), 256, 0, stream>>>(xb, wb, Q, K, VT);
    rope_kernel<<<512, 256, 0, stream>>>(Q, K);
    attn_kernel<<<dim3(80, 32), 256, 0, stream>>>(Q, K, VT, paO, ml);
    combine_kernel<<<dim3(32, 32), 256, 0, stream>>>(paO, ml, Y);
    oproj_kernel<<<dim3(8, 64), 256, 0, stream>>>(Y, wb + 3 * 1048576, out);
}